// Round 9
// baseline (863.313 us; speedup 1.0000x reference)
//
#include <hip/hip_runtime.h>
#include <cmath>

#define B_  128
#define T_  512
#define E_  128
#define H_  128
#define G4  512   // 4*H
#define K_  9

// ---------------------------------------------------------------------------
// Kernel 1: input projection GEMM with fused embedding gather.
// proj[b][tc][n] = sum_k embed[sent[b,t]][k] * W_dir[n'][k] + (bih+bhh)[n']
// Tile: 64(M) x 64(N), 256 threads, 4x4 micro-tile (R0 compute structure).
//
// R9: K split into two 64-slices -> LDS 32KB/block -> 4 blocks/CU (16
// waves, was 2 blocks/8 waves at 18% occ). Slice 1 prefetched into regs
// during slice 0 compute (32 extra VGPRs; acc is only 16). R0's 195us had
// 3.6x slack over the ~55us DS/VALU pipe floors — exposed gather latency
// + barrier at low occupancy. More resident waves + reg-prefetch hide it.
// ---------------------------------------------------------------------------
__global__ __launch_bounds__(256, 4)
void proj_gemm(const int* __restrict__ sent, const float* __restrict__ embed,
               const float* __restrict__ Wf, const float* __restrict__ Wb,
               const float* __restrict__ bif, const float* __restrict__ bhf,
               const float* __restrict__ bib, const float* __restrict__ bhb,
               float* __restrict__ proj, int t0f, int Tc)
{
  __shared__ __align__(16) float Al[64][64];  // [k-local][m] 16KB
  __shared__ __align__(16) float Bl[64][64];  // [k-local][n] 16KB
  const int tid   = threadIdx.x;
  const int ntile = blockIdx.x;            // 0..15
  const int mtile = blockIdx.y;
  const int tpb   = Tc >> 6;               // 64-row tiles per batch element
  const int b     = mtile / tpb;
  const int toff  = (mtile - b * tpb) << 6;
  const int dir   = ntile >> 3;
  const int t0    = dir ? (T_ - t0f - Tc) : t0f;
  const float* __restrict__ W = dir ? Wb : Wf;
  const int n0 = (ntile & 7) << 6;         // row offset inside W (0..448)

  const int r  = tid & 63;                 // staged row (m for A, n for B)
  const int kc = tid >> 6;                 // 0..3, each covers 16 k's/slice
  const int t  = t0 + toff + r;
  const int vid = sent[b * T_ + t];
  const float* __restrict__ arow = embed + (size_t)vid * E_ + kc * 16;
  const float* __restrict__ brow = W + (size_t)(n0 + r) * E_ + kc * 16;

  // ---- stage slice 0 (k = 0..63)
#pragma unroll
  for (int q = 0; q < 4; ++q) {
    float4 av = *(const float4*)(arow + q * 4);
    float4 bv = *(const float4*)(brow + q * 4);
    const int k0 = kc * 16 + q * 4;
    Al[k0 + 0][r] = av.x; Al[k0 + 1][r] = av.y;
    Al[k0 + 2][r] = av.z; Al[k0 + 3][r] = av.w;
    Bl[k0 + 0][r] = bv.x; Bl[k0 + 1][r] = bv.y;
    Bl[k0 + 2][r] = bv.z; Bl[k0 + 3][r] = bv.w;
  }
  // ---- prefetch slice 1 (k = 64..127) into registers
  float4 pa[4], pb[4];
#pragma unroll
  for (int q = 0; q < 4; ++q) {
    pa[q] = *(const float4*)(arow + 64 + q * 4);
    pb[q] = *(const float4*)(brow + 64 + q * 4);
  }
  __syncthreads();

  const int mg = tid & 15, ng = tid >> 4;
  float acc[4][4] = {};
#pragma unroll 8
  for (int k = 0; k < 64; ++k) {           // slice 0 compute
    float4 a  = *(const float4*)&Al[k][mg * 4];
    float4 bb = *(const float4*)&Bl[k][ng * 4];
    acc[0][0] += a.x * bb.x; acc[0][1] += a.x * bb.y; acc[0][2] += a.x * bb.z; acc[0][3] += a.x * bb.w;
    acc[1][0] += a.y * bb.x; acc[1][1] += a.y * bb.y; acc[1][2] += a.y * bb.z; acc[1][3] += a.y * bb.w;
    acc[2][0] += a.z * bb.x; acc[2][1] += a.z * bb.y; acc[2][2] += a.z * bb.z; acc[2][3] += a.z * bb.w;
    acc[3][0] += a.w * bb.x; acc[3][1] += a.w * bb.y; acc[3][2] += a.w * bb.z; acc[3][3] += a.w * bb.w;
  }
  __syncthreads();                         // slice-0 readers done
#pragma unroll
  for (int q = 0; q < 4; ++q) {            // write slice 1 from regs
    const int k0 = kc * 16 + q * 4;
    Al[k0 + 0][r] = pa[q].x; Al[k0 + 1][r] = pa[q].y;
    Al[k0 + 2][r] = pa[q].z; Al[k0 + 3][r] = pa[q].w;
    Bl[k0 + 0][r] = pb[q].x; Bl[k0 + 1][r] = pb[q].y;
    Bl[k0 + 2][r] = pb[q].z; Bl[k0 + 3][r] = pb[q].w;
  }
  __syncthreads();
#pragma unroll 8
  for (int k = 0; k < 64; ++k) {           // slice 1 compute
    float4 a  = *(const float4*)&Al[k][mg * 4];
    float4 bb = *(const float4*)&Bl[k][ng * 4];
    acc[0][0] += a.x * bb.x; acc[0][1] += a.x * bb.y; acc[0][2] += a.x * bb.z; acc[0][3] += a.x * bb.w;
    acc[1][0] += a.y * bb.x; acc[1][1] += a.y * bb.y; acc[1][2] += a.y * bb.z; acc[1][3] += a.y * bb.w;
    acc[2][0] += a.z * bb.x; acc[2][1] += a.z * bb.y; acc[2][2] += a.z * bb.z; acc[2][3] += a.z * bb.w;
    acc[3][0] += a.w * bb.x; acc[3][1] += a.w * bb.y; acc[3][2] += a.w * bb.z; acc[3][3] += a.w * bb.w;
  }

  const float* bi = dir ? bib : bif;
  const float* bh = dir ? bhb : bhf;
  const int nl = ng * 4;
  float4 bias;
  bias.x = bi[n0 + nl + 0] + bh[n0 + nl + 0];
  bias.y = bi[n0 + nl + 1] + bh[n0 + nl + 1];
  bias.z = bi[n0 + nl + 2] + bh[n0 + nl + 2];
  bias.w = bi[n0 + nl + 3] + bh[n0 + nl + 3];
#pragma unroll
  for (int i = 0; i < 4; ++i) {
    const int tloc = toff + mg * 4 + i;
    float4 o;
    o.x = acc[i][0] + bias.x; o.y = acc[i][1] + bias.y;
    o.z = acc[i][2] + bias.z; o.w = acc[i][3] + bias.w;
    *(float4*)&proj[((size_t)(b * Tc + tloc)) * 1024 + dir * G4 + n0 + nl] = o;
  }
}

// ---------------------------------------------------------------------------
// Fast, branchless nonlinearities (v_exp_f32 + v_rcp_f32).
// ---------------------------------------------------------------------------
__device__ __forceinline__ float fast_rcp(float x) {
  return __builtin_amdgcn_rcpf(x);
}
__device__ __forceinline__ float fast_sig(float x) {
  return fast_rcp(1.f + __expf(-x));
}
__device__ __forceinline__ float fast_tanh(float x) {
  return 2.f * fast_rcp(1.f + __expf(-2.f * x)) - 1.f;
}

// ---------------------------------------------------------------------------
// Kernel 2: LSTM recurrence (R7 structure + R8 fast gates — measured 208us).
//   512 thr, 8 waves: lane l of wave w: unit u=w*16+(l&15); gp=(l>>4)&1
//   (0:i,f  1:g,o); kh=l>>5 (k half). 2 rows x 64 k per thread; k-halves
//   summed via __shfl_xor(32); gate exchange via __shfl_xor(16); one
//   barrier/step; h_hist double-buffered.
// Packed-sequence semantics: state frozen + output zeroed where t >= len.
// ---------------------------------------------------------------------------
__global__ __launch_bounds__(512, 2)
void lstm_chunk(const float* __restrict__ proj,
                const float* __restrict__ Whf, const float* __restrict__ Whb,
                const int* __restrict__ lengths,
                float* __restrict__ hs,
                float* __restrict__ sh, float* __restrict__ sc,
                int t0f, int Tc, int first)
{
  const int dir = blockIdx.x;
  const int b   = blockIdx.y;
  const int tid = threadIdx.x;
  const int l   = tid & 63;
  const int wv  = tid >> 6;
  const int u   = wv * 16 + (l & 15);      // hidden unit 0..127
  const int gp  = (l >> 4) & 1;            // 0: gates i,f   1: gates g,o
  const int kh  = l >> 5;                  // k half 0/1
  const int rowA = u + (gp ? 256 : 0);     // i or g
  const int rowB = rowA + 128;             // f or o
  const float* __restrict__ Whh = dir ? Whb : Whf;
  __shared__ __align__(16) float h_hist[2][H_];

  float wA[64], wB[64];
  {
    const float* wra = Whh + (size_t)rowA * H_ + kh * 64;
    const float* wrb = Whh + (size_t)rowB * H_ + kh * 64;
#pragma unroll
    for (int k = 0; k < 64; k += 4) {
      float4 va = *(const float4*)(wra + k);
      float4 vb = *(const float4*)(wrb + k);
      wA[k] = va.x; wA[k + 1] = va.y; wA[k + 2] = va.z; wA[k + 3] = va.w;
      wB[k] = vb.x; wB[k + 1] = vb.y; wB[k + 2] = vb.z; wB[k + 3] = vb.w;
    }
  }
#pragma unroll
  for (int k = 0; k < 64; ++k) {
    asm volatile("" : "+v"(wA[k]));
    asm volatile("" : "+v"(wB[k]));
  }

  const int len = lengths[b];
  const int t0  = dir ? (T_ - t0f - Tc) : t0f;
  const float fgp = (float)gp;
  const float kf  = 1.f + fgp;             // 1: sigmoid  2: tanh scaling
  float c = 0.f, h_reg = 0.f;
  if (!first) {
    c     = sc[(dir * B_ + b) * H_ + u];
    h_reg = sh[(dir * B_ + b) * H_ + u];
  }
  if (l < 16) h_hist[1][u] = h_reg;        // slot read by step 0
  __syncthreads();

  const float* projpA = proj + (size_t)b * Tc * 1024 + dir * G4 + rowA;
  const float* projpB = projpA + 128;
  const int tc00 = dir ? (Tc - 1) : 0;
  float pvA = projpA[(size_t)tc00 * 1024];
  float pvB = projpB[(size_t)tc00 * 1024];

  for (int s = 0; s < Tc; ++s) {
    const int tc = dir ? (Tc - 1 - s) : s;
    const int t  = t0 + tc;
    float nvA = 0.f, nvB = 0.f;
    if (s + 1 < Tc) {
      const int tcn = dir ? (Tc - 2 - s) : (s + 1);
      nvA = projpA[(size_t)tcn * 1024];
      nvB = projpB[(size_t)tcn * 1024];
    }
    const float* hp = h_hist[(s + 1) & 1] + kh * 64;   // h_{s-1}, own k-half
    float a0 = 0.f, a1 = 0.f, a2 = 0.f, a3 = 0.f;
#pragma unroll
    for (int k4 = 0; k4 < 16; ++k4) {
      float4 h4 = *(const float4*)&hp[k4 * 4];
      a0 += wA[4 * k4 + 0] * h4.x; a1 += wA[4 * k4 + 1] * h4.y;
      a0 += wA[4 * k4 + 2] * h4.z; a1 += wA[4 * k4 + 3] * h4.w;
      a2 += wB[4 * k4 + 0] * h4.x; a3 += wB[4 * k4 + 1] * h4.y;
      a2 += wB[4 * k4 + 2] * h4.z; a3 += wB[4 * k4 + 3] * h4.w;
    }
    float sA = a0 + a1; sA += __shfl_xor(sA, 32); sA += pvA;
    float sB = a2 + a3; sB += __shfl_xor(sB, 32); sB += pvB;
    // gA: sigmoid (gp=0) or tanh (gp=1), branchless; gB: always sigmoid.
    const float gA = kf * fast_rcp(1.f + __expf(-kf * sA)) - fgp;
    const float gB = fast_sig(sB);
    const float xA = __shfl_xor(gA, 16);
    const float xB = __shfl_xor(gB, 16);
    const float gi = gp ? xA : gA;
    const float gf = gp ? xB : gB;
    const float gg = gp ? gA : xA;
    const float go = gp ? gB : xB;
    const float cn = gf * c + gi * gg;
    const float hn = go * fast_tanh(cn);
    const bool  m  = (t < len);
    c     = m ? cn : c;
    h_reg = m ? hn : h_reg;
    if (l < 16) {
      h_hist[s & 1][u] = h_reg;
      hs[(size_t)(b * T_ + t) * 256 + dir * H_ + u] = m ? hn : 0.f;
    }
    __syncthreads();
    pvA = nvA; pvB = nvB;
  }
  if (l < 16 && wv == (u >> 4)) {          // one writer per unit
    sh[(dir * B_ + b) * H_ + u] = h_reg;
    sc[(dir * B_ + b) * H_ + u] = c;
  }
}

// ---------------------------------------------------------------------------
// Kernel 3: emissions em[m][k] = hs[m][:] . W_out[k][:] + b_out[k]
// ---------------------------------------------------------------------------
__global__ __launch_bounds__(256)
void emis_kernel(const float* __restrict__ hs, const float* __restrict__ Wout,
                 const float* __restrict__ bout, float* __restrict__ em)
{
  __shared__ __align__(16) float Wl[K_ * 256];
  const int tid = threadIdx.x;
  for (int i = tid; i < K_ * 256; i += 256) Wl[i] = Wout[i];
  __syncthreads();
  const int m = blockIdx.x * 256 + tid;
  const float* h = hs + (size_t)m * 256;
  float acc[K_] = {};
#pragma unroll 4
  for (int kk = 0; kk < 64; ++kk) {
    float4 h4 = *(const float4*)(h + kk * 4);
#pragma unroll
    for (int k9 = 0; k9 < K_; ++k9) {
      float4 w4 = *(const float4*)&Wl[k9 * 256 + kk * 4];
      acc[k9] += h4.x * w4.x + h4.y * w4.y + h4.z * w4.z + h4.w * w4.w;
    }
  }
#pragma unroll
  for (int k9 = 0; k9 < K_; ++k9) em[(size_t)m * K_ + k9] = acc[k9] + bout[k9];
}

// ---------------------------------------------------------------------------
// Kernel 4: Viterbi decode, one 64-lane wave per batch element.
// ---------------------------------------------------------------------------
__global__ __launch_bounds__(64)
void viterbi_kernel(const float* __restrict__ em, const int* __restrict__ lengths,
                    const float* __restrict__ st, const float* __restrict__ en,
                    const float* __restrict__ trans, int* __restrict__ tags)
{
  const int b    = blockIdx.x;
  const int lane = threadIdx.x;
  __shared__ unsigned char hist[(T_ - 1) * 16];
  const int len = lengths[b];
  float tr[K_];
#pragma unroll
  for (int j = 0; j < K_; ++j) tr[j] = (lane < K_) ? trans[j * K_ + lane] : 0.f;
  float s = (lane < K_) ? st[lane] + em[(size_t)(b * T_) * K_ + lane] : -1e30f;
  for (int t = 1; t < len; ++t) {
    float best = -1e30f; int bj = 0;
#pragma unroll
    for (int j = 0; j < K_; ++j) {
      float v = __shfl(s, j) + tr[j];
      if (v > best) { best = v; bj = j; }    // strict > == first-max (argmax)
    }
    if (lane < K_) {
      s = best + em[(size_t)(b * T_ + t) * K_ + lane];
      hist[(t - 1) * 16 + lane] = (unsigned char)bj;
    }
  }
  float fs = (lane < K_) ? s + en[lane] : -1e30f;
  float best = -1e30f; int last = 0;
#pragma unroll
  for (int j = 0; j < K_; ++j) {
    float v = __shfl(fs, j);
    if (v > best) { best = v; last = j; }
  }
  __syncthreads();                            // hist visible to lane 0
  if (lane == 0) {
    int tag = last;
    tags[b * T_ + len - 1] = tag;
    for (int t = len - 2; t >= 0; --t) {
      tag = hist[t * 16 + tag];
      tags[b * T_ + t] = tag;
    }
  }
  for (int t = len + lane; t < T_; t += 64) tags[b * T_ + t] = 0;
}

// ---------------------------------------------------------------------------
extern "C" void kernel_launch(void* const* d_in, const int* in_sizes, int n_in,
                              void* d_out, int out_size, void* d_ws, size_t ws_size,
                              hipStream_t stream)
{
  const int*   sent  = (const int*)d_in[0];
  const int*   lens  = (const int*)d_in[1];
  const float* embed = (const float*)d_in[2];
  const float* Wif   = (const float*)d_in[3];
  const float* Whf   = (const float*)d_in[4];
  const float* bif   = (const float*)d_in[5];
  const float* bhf   = (const float*)d_in[6];
  const float* Wib   = (const float*)d_in[7];
  const float* Whb   = (const float*)d_in[8];
  const float* bib   = (const float*)d_in[9];
  const float* bhb   = (const float*)d_in[10];
  const float* Wout  = (const float*)d_in[11];
  const float* bout  = (const float*)d_in[12];
  const float* stt   = (const float*)d_in[13];
  const float* ent   = (const float*)d_in[14];
  const float* trans = (const float*)d_in[15];
  int* tags = (int*)d_out;

  // workspace layout (floats): hs | em | state_h | state_c | proj(chunked)
  float* ws   = (float*)d_ws;
  float* hs   = ws;                                  // B*T*256   (67.1 MB)
  float* em   = hs + (size_t)B_ * T_ * 256;          // B*T*9     ( 2.4 MB)
  float* sh   = em + (size_t)B_ * T_ * K_;           // 2*B*H carry h
  float* sc   = sh + (size_t)2 * B_ * H_;            // 2*B*H carry c
  float* proj = sc + (size_t)2 * B_ * H_;
  const size_t fixed_bytes = (size_t)(proj - ws) * sizeof(float);

  // largest time-chunk whose proj buffer fits the workspace (floor at 64)
  int Tc = 512;
  while (Tc > 64 && fixed_bytes + (size_t)B_ * Tc * 1024 * sizeof(float) > ws_size)
    Tc >>= 1;

  const int nch = T_ / Tc;
  for (int c2 = 0; c2 < nch; ++c2) {
    const int t0f = c2 * Tc;
    dim3 g1(16, B_ * (Tc >> 6));
    hipLaunchKernelGGL(proj_gemm, g1, dim3(256), 0, stream,
                       sent, embed, Wif, Wib, bif, bhf, bib, bhb, proj, t0f, Tc);
    dim3 g2(2, B_);
    hipLaunchKernelGGL(lstm_chunk, g2, dim3(512), 0, stream,
                       proj, Whf, Whb, lens, hs, sh, sc, t0f, Tc, (int)(c2 == 0));
  }
  hipLaunchKernelGGL(emis_kernel, dim3((B_ * T_) / 256), dim3(256), 0, stream,
                     hs, Wout, bout, em);
  hipLaunchKernelGGL(viterbi_kernel, dim3(B_), dim3(64), 0, stream,
                     em, lens, stt, ent, trans, tags);
}

// Round 10
// 850.902 us; speedup vs baseline: 1.0146x; 1.0146x over previous
//
#include <hip/hip_runtime.h>
#include <cmath>

#define B_  128
#define T_  512
#define E_  128
#define H_  128
#define G4  512   // 4*H
#define K_  9

// ---------------------------------------------------------------------------
// Kernel 0a: gather + transpose embeddings once per launch.
//   Xt[k][b*T+t] = embed[sent[b][t]][k]   (33.6 MB, fp32 exact)
// The random 51-MB-table gather is paid ONCE here (coalesced writes),
// instead of 16x per mtile inside proj_gemm with 64-transaction loads.
// ---------------------------------------------------------------------------
__global__ __launch_bounds__(256)
void gather_x(const int* __restrict__ sent, const float* __restrict__ embed,
              float* __restrict__ Xt)
{
  const int m = blockIdx.x * 256 + threadIdx.x;   // 0 .. B*T-1  (b*T+t)
  const int vid = sent[m];
  const float* er = embed + (size_t)vid * E_;
  const size_t MT = (size_t)B_ * T_;
#pragma unroll
  for (int q = 0; q < 32; ++q) {
    float4 v = *(const float4*)(er + q * 4);      // gather read (once)
    Xt[(size_t)(q * 4 + 0) * MT + m] = v.x;       // coalesced writes
    Xt[(size_t)(q * 4 + 1) * MT + m] = v.y;
    Xt[(size_t)(q * 4 + 2) * MT + m] = v.z;
    Xt[(size_t)(q * 4 + 3) * MT + m] = v.w;
  }
}

// ---------------------------------------------------------------------------
// Kernel 0b: transpose LSTM input weights once.  Wt[k][n], n<512 -> Wf[n][k],
// n>=512 -> Wb[n-512][k].  128x1024 fp32 = 512 KB.
// ---------------------------------------------------------------------------
__global__ __launch_bounds__(256)
void transpose_w(const float* __restrict__ Wf, const float* __restrict__ Wb,
                 float* __restrict__ Wt)
{
  const int idx = blockIdx.x * 256 + threadIdx.x;  // over 128*1024
  const int k = idx >> 10, n = idx & 1023;
  Wt[idx] = (n < 512) ? Wf[n * E_ + k] : Wb[(n - 512) * E_ + k];
}

// ---------------------------------------------------------------------------
// Kernel 1: input projection GEMM.
// proj[b][tc][n] = sum_k Xt[k][m] * Wt[k][n] + (bih+bhh)[n']
// Tile 64(M) x 64(N) x 128(K), 256 threads, 4x4 micro-tile — the R0 compute
// structure (best measured), with R10 staging: loads from pre-transposed
// Xt/Wt so consecutive lanes hit consecutive addresses (16 transactions per
// wave-instr instead of 64) and LDS writes are ds_write_b128.
// ---------------------------------------------------------------------------
__global__ __launch_bounds__(256, 2)
void proj_gemm(const float* __restrict__ Xt, const float* __restrict__ Wt,
               const float* __restrict__ bif, const float* __restrict__ bhf,
               const float* __restrict__ bib, const float* __restrict__ bhb,
               float* __restrict__ proj, int t0f, int Tc)
{
  __shared__ __align__(16) float Al[128 * 64];  // [k][m]
  __shared__ __align__(16) float Bl[128 * 64];  // [k][n]
  const int tid   = threadIdx.x;
  const int ntile = blockIdx.x;            // 0..15
  const int mtile = blockIdx.y;
  const int tpb   = Tc >> 6;               // 64-row tiles per batch element
  const int b     = mtile / tpb;
  const int toff  = (mtile - b * tpb) << 6;
  const int dir   = ntile >> 3;
  const int t0    = dir ? (T_ - t0f - Tc) : t0f;
  const int n0    = (ntile & 7) << 6;      // col offset within direction

  // ---- stage A and B, k-major, coalesced from Xt/Wt
  {
    const int r4 = tid & 15;               // 16-B quad within 64-wide tile
    const int ks = tid >> 4;               // 0..15 -> k = ks*8 .. +8
    const size_t MT = (size_t)B_ * T_;
    const int mbase = b * T_ + t0 + toff;  // 64-aligned
    const int nbase = dir * 512 + n0;
#pragma unroll
    for (int p = 0; p < 8; ++p) {
      const int k = ks * 8 + p;
      float4 a4 = *(const float4*)(Xt + (size_t)k * MT + mbase + r4 * 4);
      float4 b4 = *(const float4*)(Wt + k * 1024 + nbase + r4 * 4);
      *(float4*)&Al[k * 64 + r4 * 4] = a4;
      *(float4*)&Bl[k * 64 + r4 * 4] = b4;
    }
  }
  __syncthreads();

  const int mg = tid & 15, ng = tid >> 4;
  float acc[4][4] = {};
#pragma unroll 8
  for (int k = 0; k < 128; ++k) {
    float4 a  = *(const float4*)&Al[k * 64 + mg * 4];
    float4 bb = *(const float4*)&Bl[k * 64 + ng * 4];
    acc[0][0] += a.x * bb.x; acc[0][1] += a.x * bb.y; acc[0][2] += a.x * bb.z; acc[0][3] += a.x * bb.w;
    acc[1][0] += a.y * bb.x; acc[1][1] += a.y * bb.y; acc[1][2] += a.y * bb.z; acc[1][3] += a.y * bb.w;
    acc[2][0] += a.z * bb.x; acc[2][1] += a.z * bb.y; acc[2][2] += a.z * bb.z; acc[2][3] += a.z * bb.w;
    acc[3][0] += a.w * bb.x; acc[3][1] += a.w * bb.y; acc[3][2] += a.w * bb.z; acc[3][3] += a.w * bb.w;
  }

  const float* bi = dir ? bib : bif;
  const float* bh = dir ? bhb : bhf;
  const int nl = ng * 4;
  float4 bias;
  bias.x = bi[n0 + nl + 0] + bh[n0 + nl + 0];
  bias.y = bi[n0 + nl + 1] + bh[n0 + nl + 1];
  bias.z = bi[n0 + nl + 2] + bh[n0 + nl + 2];
  bias.w = bi[n0 + nl + 3] + bh[n0 + nl + 3];
#pragma unroll
  for (int i = 0; i < 4; ++i) {
    const int tloc = toff + mg * 4 + i;
    float4 o;
    o.x = acc[i][0] + bias.x; o.y = acc[i][1] + bias.y;
    o.z = acc[i][2] + bias.z; o.w = acc[i][3] + bias.w;
    *(float4*)&proj[((size_t)(b * Tc + tloc)) * 1024 + dir * G4 + n0 + nl] = o;
  }
}

// ---------------------------------------------------------------------------
// Fast, branchless nonlinearities (v_exp_f32 + v_rcp_f32).
// ---------------------------------------------------------------------------
__device__ __forceinline__ float fast_rcp(float x) {
  return __builtin_amdgcn_rcpf(x);
}
__device__ __forceinline__ float fast_sig(float x) {
  return fast_rcp(1.f + __expf(-x));
}
__device__ __forceinline__ float fast_tanh(float x) {
  return 2.f * fast_rcp(1.f + __expf(-2.f * x)) - 1.f;
}

// ---------------------------------------------------------------------------
// Kernel 2: LSTM recurrence (R7 structure + R8 fast gates — measured 206us,
// do not touch).  512 thr, 8 waves: unit u=wv*16+(l&15); gp=(l>>4)&1
// (0:i,f 1:g,o); kh=l>>5. 2 rows x 64 k per thread; k-halves via
// __shfl_xor(32); gate exchange via __shfl_xor(16); one barrier/step.
// Packed-sequence semantics: state frozen + output zeroed where t >= len.
// ---------------------------------------------------------------------------
__global__ __launch_bounds__(512, 2)
void lstm_chunk(const float* __restrict__ proj,
                const float* __restrict__ Whf, const float* __restrict__ Whb,
                const int* __restrict__ lengths,
                float* __restrict__ hs,
                float* __restrict__ sh, float* __restrict__ sc,
                int t0f, int Tc, int first)
{
  const int dir = blockIdx.x;
  const int b   = blockIdx.y;
  const int tid = threadIdx.x;
  const int l   = tid & 63;
  const int wv  = tid >> 6;
  const int u   = wv * 16 + (l & 15);      // hidden unit 0..127
  const int gp  = (l >> 4) & 1;            // 0: gates i,f   1: gates g,o
  const int kh  = l >> 5;                  // k half 0/1
  const int rowA = u + (gp ? 256 : 0);     // i or g
  const int rowB = rowA + 128;             // f or o
  const float* __restrict__ Whh = dir ? Whb : Whf;
  __shared__ __align__(16) float h_hist[2][H_];

  float wA[64], wB[64];
  {
    const float* wra = Whh + (size_t)rowA * H_ + kh * 64;
    const float* wrb = Whh + (size_t)rowB * H_ + kh * 64;
#pragma unroll
    for (int k = 0; k < 64; k += 4) {
      float4 va = *(const float4*)(wra + k);
      float4 vb = *(const float4*)(wrb + k);
      wA[k] = va.x; wA[k + 1] = va.y; wA[k + 2] = va.z; wA[k + 3] = va.w;
      wB[k] = vb.x; wB[k + 1] = vb.y; wB[k + 2] = vb.z; wB[k + 3] = vb.w;
    }
  }
#pragma unroll
  for (int k = 0; k < 64; ++k) {
    asm volatile("" : "+v"(wA[k]));
    asm volatile("" : "+v"(wB[k]));
  }

  const int len = lengths[b];
  const int t0  = dir ? (T_ - t0f - Tc) : t0f;
  const float fgp = (float)gp;
  const float kf  = 1.f + fgp;             // 1: sigmoid  2: tanh scaling
  float c = 0.f, h_reg = 0.f;
  if (!first) {
    c     = sc[(dir * B_ + b) * H_ + u];
    h_reg = sh[(dir * B_ + b) * H_ + u];
  }
  if (l < 16) h_hist[1][u] = h_reg;        // slot read by step 0
  __syncthreads();

  const float* projpA = proj + (size_t)b * Tc * 1024 + dir * G4 + rowA;
  const float* projpB = projpA + 128;
  const int tc00 = dir ? (Tc - 1) : 0;
  float pvA = projpA[(size_t)tc00 * 1024];
  float pvB = projpB[(size_t)tc00 * 1024];

  for (int s = 0; s < Tc; ++s) {
    const int tc = dir ? (Tc - 1 - s) : s;
    const int t  = t0 + tc;
    float nvA = 0.f, nvB = 0.f;
    if (s + 1 < Tc) {
      const int tcn = dir ? (Tc - 2 - s) : (s + 1);
      nvA = projpA[(size_t)tcn * 1024];
      nvB = projpB[(size_t)tcn * 1024];
    }
    const float* hp = h_hist[(s + 1) & 1] + kh * 64;   // h_{s-1}, own k-half
    float a0 = 0.f, a1 = 0.f, a2 = 0.f, a3 = 0.f;
#pragma unroll
    for (int k4 = 0; k4 < 16; ++k4) {
      float4 h4 = *(const float4*)&hp[k4 * 4];
      a0 += wA[4 * k4 + 0] * h4.x; a1 += wA[4 * k4 + 1] * h4.y;
      a0 += wA[4 * k4 + 2] * h4.z; a1 += wA[4 * k4 + 3] * h4.w;
      a2 += wB[4 * k4 + 0] * h4.x; a3 += wB[4 * k4 + 1] * h4.y;
      a2 += wB[4 * k4 + 2] * h4.z; a3 += wB[4 * k4 + 3] * h4.w;
    }
    float sA = a0 + a1; sA += __shfl_xor(sA, 32); sA += pvA;
    float sB = a2 + a3; sB += __shfl_xor(sB, 32); sB += pvB;
    // gA: sigmoid (gp=0) or tanh (gp=1), branchless; gB: always sigmoid.
    const float gA = kf * fast_rcp(1.f + __expf(-kf * sA)) - fgp;
    const float gB = fast_sig(sB);
    const float xA = __shfl_xor(gA, 16);
    const float xB = __shfl_xor(gB, 16);
    const float gi = gp ? xA : gA;
    const float gf = gp ? xB : gB;
    const float gg = gp ? gA : xA;
    const float go = gp ? gB : xB;
    const float cn = gf * c + gi * gg;
    const float hn = go * fast_tanh(cn);
    const bool  m  = (t < len);
    c     = m ? cn : c;
    h_reg = m ? hn : h_reg;
    if (l < 16) {
      h_hist[s & 1][u] = h_reg;
      hs[(size_t)(b * T_ + t) * 256 + dir * H_ + u] = m ? hn : 0.f;
    }
    __syncthreads();
    pvA = nvA; pvB = nvB;
  }
  if (l < 16 && wv == (u >> 4)) {          // one writer per unit
    sh[(dir * B_ + b) * H_ + u] = h_reg;
    sc[(dir * B_ + b) * H_ + u] = c;
  }
}

// ---------------------------------------------------------------------------
// Kernel 3: emissions em[m][k] = hs[m][:] . W_out[k][:] + b_out[k]
// ---------------------------------------------------------------------------
__global__ __launch_bounds__(256)
void emis_kernel(const float* __restrict__ hs, const float* __restrict__ Wout,
                 const float* __restrict__ bout, float* __restrict__ em)
{
  __shared__ __align__(16) float Wl[K_ * 256];
  const int tid = threadIdx.x;
  for (int i = tid; i < K_ * 256; i += 256) Wl[i] = Wout[i];
  __syncthreads();
  const int m = blockIdx.x * 256 + tid;
  const float* h = hs + (size_t)m * 256;
  float acc[K_] = {};
#pragma unroll 4
  for (int kk = 0; kk < 64; ++kk) {
    float4 h4 = *(const float4*)(h + kk * 4);
#pragma unroll
    for (int k9 = 0; k9 < K_; ++k9) {
      float4 w4 = *(const float4*)&Wl[k9 * 256 + kk * 4];
      acc[k9] += h4.x * w4.x + h4.y * w4.y + h4.z * w4.z + h4.w * w4.w;
    }
  }
#pragma unroll
  for (int k9 = 0; k9 < K_; ++k9) em[(size_t)m * K_ + k9] = acc[k9] + bout[k9];
}

// ---------------------------------------------------------------------------
// Kernel 4: Viterbi decode, one 64-lane wave per batch element.
// ---------------------------------------------------------------------------
__global__ __launch_bounds__(64)
void viterbi_kernel(const float* __restrict__ em, const int* __restrict__ lengths,
                    const float* __restrict__ st, const float* __restrict__ en,
                    const float* __restrict__ trans, int* __restrict__ tags)
{
  const int b    = blockIdx.x;
  const int lane = threadIdx.x;
  __shared__ unsigned char hist[(T_ - 1) * 16];
  const int len = lengths[b];
  float tr[K_];
#pragma unroll
  for (int j = 0; j < K_; ++j) tr[j] = (lane < K_) ? trans[j * K_ + lane] : 0.f;
  float s = (lane < K_) ? st[lane] + em[(size_t)(b * T_) * K_ + lane] : -1e30f;
  for (int t = 1; t < len; ++t) {
    float best = -1e30f; int bj = 0;
#pragma unroll
    for (int j = 0; j < K_; ++j) {
      float v = __shfl(s, j) + tr[j];
      if (v > best) { best = v; bj = j; }    // strict > == first-max (argmax)
    }
    if (lane < K_) {
      s = best + em[(size_t)(b * T_ + t) * K_ + lane];
      hist[(t - 1) * 16 + lane] = (unsigned char)bj;
    }
  }
  float fs = (lane < K_) ? s + en[lane] : -1e30f;
  float best = -1e30f; int last = 0;
#pragma unroll
  for (int j = 0; j < K_; ++j) {
    float v = __shfl(fs, j);
    if (v > best) { best = v; last = j; }
  }
  __syncthreads();                            // hist visible to lane 0
  if (lane == 0) {
    int tag = last;
    tags[b * T_ + len - 1] = tag;
    for (int t = len - 2; t >= 0; --t) {
      tag = hist[t * 16 + tag];
      tags[b * T_ + t] = tag;
    }
  }
  for (int t = len + lane; t < T_; t += 64) tags[b * T_ + t] = 0;
}

// ---------------------------------------------------------------------------
extern "C" void kernel_launch(void* const* d_in, const int* in_sizes, int n_in,
                              void* d_out, int out_size, void* d_ws, size_t ws_size,
                              hipStream_t stream)
{
  const int*   sent  = (const int*)d_in[0];
  const int*   lens  = (const int*)d_in[1];
  const float* embed = (const float*)d_in[2];
  const float* Wif   = (const float*)d_in[3];
  const float* Whf   = (const float*)d_in[4];
  const float* bif   = (const float*)d_in[5];
  const float* bhf   = (const float*)d_in[6];
  const float* Wib   = (const float*)d_in[7];
  const float* Whb   = (const float*)d_in[8];
  const float* bib   = (const float*)d_in[9];
  const float* bhb   = (const float*)d_in[10];
  const float* Wout  = (const float*)d_in[11];
  const float* bout  = (const float*)d_in[12];
  const float* stt   = (const float*)d_in[13];
  const float* ent   = (const float*)d_in[14];
  const float* trans = (const float*)d_in[15];
  int* tags = (int*)d_out;

  // workspace layout (floats): hs | em | sh | sc | Xt | Wt | proj(chunked)
  float* ws   = (float*)d_ws;
  float* hs   = ws;                                  // B*T*256   (67.1 MB)
  float* em   = hs + (size_t)B_ * T_ * 256;          // B*T*9     ( 2.4 MB)
  float* sh   = em + (size_t)B_ * T_ * K_;           // 2*B*H carry h
  float* sc   = sh + (size_t)2 * B_ * H_;            // 2*B*H carry c
  float* Xt   = sc + (size_t)2 * B_ * H_;            // 128*B*T   (33.6 MB)
  float* Wt   = Xt + (size_t)E_ * B_ * T_;           // 128*1024  ( 0.5 MB)
  float* proj = Wt + (size_t)E_ * 1024;
  const size_t fixed_bytes = (size_t)(proj - ws) * sizeof(float);

  // largest time-chunk whose proj buffer fits the workspace (floor at 64)
  int Tc = 512;
  while (Tc > 64 && fixed_bytes + (size_t)B_ * Tc * 1024 * sizeof(float) > ws_size)
    Tc >>= 1;

  // one-time operand preparation
  hipLaunchKernelGGL(gather_x, dim3((B_ * T_) / 256), dim3(256), 0, stream,
                     sent, embed, Xt);
  hipLaunchKernelGGL(transpose_w, dim3((E_ * 1024) / 256), dim3(256), 0, stream,
                     Wif, Wib, Wt);

  const int nch = T_ / Tc;
  for (int c2 = 0; c2 < nch; ++c2) {
    const int t0f = c2 * Tc;
    dim3 g1(16, B_ * (Tc >> 6));
    hipLaunchKernelGGL(proj_gemm, g1, dim3(256), 0, stream,
                       Xt, Wt, bif, bhf, bib, bhb, proj, t0f, Tc);
    dim3 g2(2, B_);
    hipLaunchKernelGGL(lstm_chunk, g2, dim3(512), 0, stream,
                       proj, Whf, Whb, lens, hs, sh, sc, t0f, Tc, (int)(c2 == 0));
  }
  hipLaunchKernelGGL(emis_kernel, dim3((B_ * T_) / 256), dim3(256), 0, stream,
                     hs, Wout, bout, em);
  hipLaunchKernelGGL(viterbi_kernel, dim3(B_), dim3(64), 0, stream,
                     em, lens, stt, ent, trans, tags);
}